// Round 7
// baseline (134.654 us; speedup 1.0000x reference)
//
#include <hip/hip_runtime.h>
#include <hip/hip_bf16.h>

// R19: MEASUREMENT ROUND == R17 exactly (2-barrier transposed-logit, simple
// store barrier; dur 111.18) + a WARM DUPLICATE of the C'->D->bar->F'
// pipeline inserted before G (3rd barrier region for the dup).
// == Methodology correction (this round's key finding) ==
// Reconciling dur_us vs profiled dispatch times across R12-R18: dur-kernel
// offset is ~69-70us in EVERY round except R16 (45.5). Unprofiled, R16's 4
// dummy barriers cost 119.4-113.9 = 5.5us => barrier B ~= 1.37us, NOT 7.3.
// rocprofv3 inflates poll-heavy dispatches ~5x. Cross-checks: R17 = R15 -
// 2x1.37 predicts 111.2, measured 111.18 (exact); R13/R14 spill re-derives
// consistently (+15us). LEDGER: dur_us is ground truth; profiled times of
// polling code are artifacts; barriers are ~1.4us (R18's distributed barrier
// +0.9us -> reverted to R17 form).
// Consequence: phases ~= 38-39us, INVARIANT across all restructures since
// R12, vs a ~8-10us warm-work model. This round bisects: the duplicate
// segment re-executes the full inter-barrier pipeline with warm data/LDS
// (idempotent - every phase verified to recompute identical values; w_eff
// reads only sk1/cw; plog2/table writes rewrite same values).
//   dur_R19 - 111.2 - 1.37 = WARM cost of C'+D+F'.
// Pre-committed: warm<=6us (dur<=119) -> 39us is first-touch/cold-latency
// -> attack entry critical path + fetch volume + code size. warm>=12us
// (dur>=125) -> serial chain -> merge phases, all-wave parallelism, fewer
// syncthreads.
// Phases: entry prefetch -> A -> bar1 -> C' -> D -> bar2 -> F' ->
//         [C'2 -> D2 -> bar3 -> F'2] (dup) -> G
// Ledger (measured): agent acquire/release fences forbidden (R4); cross-block
// data sc1 relaxed-agent only (R8); no dynamic-indexed register arrays (R7);
// no rolled global-load loops (R11); entry prefetch of all static loads
// (R12); NO long-lived prefetch regs across barriers - stage via LDS
// (R14/R15); barrier ~1.4us store-based (R16 corrected), distribution
// neutral (R18). Deadlock safety: 128 blocks x 256 thr, launch_bounds(256,1),
// ~46KB LDS -> co-resident. Barrier state (3 x 1KB) zeroed each call.

#define GRID 128

#define LD1(p)     __hip_atomic_load((p), __ATOMIC_RELAXED, __HIP_MEMORY_SCOPE_AGENT)
#define ST1(p, v)  __hip_atomic_store((p), (v), __ATOMIC_RELAXED, __HIP_MEMORY_SCOPE_AGENT)

__device__ __forceinline__ float sigmoidf_(float z) {
    return 1.0f / (1.0f + expf(-z));
}

// base: 256 words (1KB). arrival[0..127]; release flag at word 160.
// No atomics anywhere: stores + loads only. (R12-validated, R17 form)
__device__ __forceinline__ void gbar(unsigned* base, int blk, int t) {
    asm volatile("s_waitcnt vmcnt(0)" ::: "memory");   // data sc1 stores visible
    __syncthreads();
    if (t == 0) ST1(base + blk, 1u);                   // arrival store, own word
    if (blk == 0) {
        if (t < 128) {                                 // 2 waves poll 128 words
            while (LD1(base + t) == 0u)
                __builtin_amdgcn_s_sleep(8);
        }
        __syncthreads();
        if (t == 0) ST1(base + 160, 1u);               // release flag, own line
    } else {
        if (t == 0) {
            while (LD1(base + 160) == 0u)
                __builtin_amdgcn_s_sleep(8);
        }
        __syncthreads();
    }
    asm volatile("" ::: "memory");
    __syncthreads();
}

// entry tap loads for one key stage (2 samples/wave; sample = blk*4+wv+rep*512)
__device__ __forceinline__ void key_prefetch(const float* __restrict__ in,
                                             int mul, int dbl, int blk,
                                             int lane, int wv,
                                             float xa[2], float xb[2]) {
#pragma unroll
    for (int rep = 0; rep < 2; ++rep) {
        int s = blk * 4 + wv + rep * 512;
        int ii = s >> 5, jj = s & 31;
        int qy = (ii * mul) >> 5, qx = (jj * mul) >> 5;
        int by = dbl ? 2 * qy : qy - 1;
        int bx = dbl ? 2 * qx : qx - 1;
        {
            int l = lane;                    // < 64 < 75: always a valid tap
            int ci = l / 25, rm = l % 25, r = rm / 5, cc = rm % 5;
            int y = by + r, x = bx + cc;
            xa[rep] = ((unsigned)y < 1024u && (unsigned)x < 1024u)
                      ? 2.0f * in[ci * 1048576 + y * 1024 + x] - 1.0f : 0.f;
        }
        xb[rep] = 0.f;
        if (lane < 11) {
            int l = lane + 64;
            int ci = l / 25, rm = l % 25, r = rm / 5, cc = rm % 5;
            int y = by + r, x = bx + cc;
            xb[rep] = ((unsigned)y < 1024u && (unsigned)x < 1024u)
                      ? 2.0f * in[ci * 1048576 + y * 1024 + x] - 1.0f : 0.f;
        }
    }
}

// key values from prefetched taps -> skv LDS (24 floats: [c*8 + rep*4 + wv])
__device__ __forceinline__ void key_stage(const float* __restrict__ sw,
                                          const float* __restrict__ sb,
                                          const float xa[2], const float xb[2],
                                          float* __restrict__ skv,
                                          int lane, int wv) {
#pragma unroll
    for (int rep = 0; rep < 2; ++rep) {
        float p0 = xa[rep] * sw[lane];
        float p1 = xa[rep] * sw[75 + lane];
        float p2 = xa[rep] * sw[150 + lane];
        if (lane < 11) {
            p0 += xb[rep] * sw[64 + lane];
            p1 += xb[rep] * sw[139 + lane];
            p2 += xb[rep] * sw[214 + lane];
        }
#pragma unroll
        for (int off = 32; off > 0; off >>= 1) {
            p0 += __shfl_xor(p0, off, 64);
            p1 += __shfl_xor(p1, off, 64);
            p2 += __shfl_xor(p2, off, 64);
        }
        if (lane == 0) {
            skv[0 * 8 + rep * 4 + wv] = sigmoidf_(p0 + sb[0]);
            skv[1 * 8 + rep * 4 + wv] = sigmoidf_(p1 + sb[1]);
            skv[2 * 8 + rep * 4 + wv] = sigmoidf_(p2 + sb[2]);
        }
    }
}

// softmax over slog[0..99] (LDS) -> satt (LDS); runs in every block
__device__ __forceinline__ void softmax_lds(const float* __restrict__ slog,
                                            float* __restrict__ satt,
                                            int lane, int wv) {
    if (wv == 0) {
        float v1 = slog[lane];
        float v2 = (lane + 64 < 100) ? slog[lane + 64] : -3.4e38f;
        float mx = fmaxf(v1, v2);
#pragma unroll
        for (int off = 32; off > 0; off >>= 1) mx = fmaxf(mx, __shfl_xor(mx, off, 64));
        float e1 = expf(v1 - mx);
        float e2 = (lane + 64 < 100) ? expf(v2 - mx) : 0.f;
        float s = e1 + e2;
#pragma unroll
        for (int off = 32; off > 0; off >>= 1) s += __shfl_xor(s, off, 64);
        float inv = 1.0f / s;
        satt[lane] = e1 * inv;
        if (lane + 64 < 100) satt[lane + 64] = e2 * inv;
    }
    __syncthreads();
}

__global__ __launch_bounds__(256, 1) void k_fused(
    const float* __restrict__ in, const float* __restrict__ cw,
    const float* __restrict__ cb, const float* __restrict__ keys,
    const float* __restrict__ vals, float* __restrict__ out,
    float* __restrict__ ws, unsigned* __restrict__ ctr)
{
    __shared__ float smem[11380];
    float* sk1  = smem;          // 225  kern1 (persists C'->F')
    float* sk2  = smem + 232;    // 225  kern2
    float* satt = smem + 464;    // 100  softmax
    float* sw   = smem + 568;    // 225  conv weights, then w_eff
    float* sb   = smem + 800;    // 3    bias
    float* sW   = smem + 808;    // 1521 composite W [(ci*3+o)*169 + e*13+f]
    float* sWy  = smem + 2332;   // 117
    float* sWx  = smem + 2452;   // 117
    float* sWxy = smem + 2572;   // 9
    float* skv  = smem + 2584;   // 24   block's key samples [c*8+rep*4+wv]
    float* slog = smem + 2608;   // 128  reduced logits
    float* skc  = smem + 2736;   // 2500 keys cols [t*25 + c*8+r*4+w], pad 25
    float* sgx  = smem + 5236;   // 6144 G taps [((ch*4+k)*4+l)*128 + j]

    float* plog1 = ws;           // [128 blocks][128 stride], 100 used
    float* plog2 = ws + 16384;

    const int t = threadIdx.x, lane = t & 63, wv = t >> 6;
    const int blk = blockIdx.x;

    // ---- entry prefetch: key-stage taps (xa2/xb2 live across bar1, 4 regs) ----
    float xa1[2], xb1[2], xa2[2], xb2[2];
    key_prefetch(in, 510, 1, blk, lane, wv, xa1, xb1);
    key_prefetch(in, 1022, 0, blk, lane, wv, xa2, xb2);

    // ---- entry: keys columns for this block's 8 samples -> LDS (R14 fix) ----
    if (t < 100) {
        const float* kr = keys + t * 3072 + blk * 4;
#pragma unroll
        for (int c = 0; c < 3; ++c)
#pragma unroll
            for (int r = 0; r < 2; ++r) {
                float4 kk = *reinterpret_cast<const float4*>(kr + c * 1024 + r * 512);
                int o = t * 25 + c * 8 + r * 4;
                skc[o]     = kk.x;
                skc[o + 1] = kk.y;
                skc[o + 2] = kk.z;
                skc[o + 3] = kk.w;
            }
    }

    // ---- entry: stage G taps into LDS (registers die here; R14 lesson) ----
    const int j = t & 127, h = t >> 7;
    const int R = (blk * 4093) >> 7;
    const int C = (j * 4093) >> 7;
    const int ybase = (R + 6) >> 2, r0 = (R + 6) & 3, nk = (r0 == 0) ? 4 : 3;
    const int xbase = (C + 6) >> 2, f0 = (C + 6) & 3, nl = (f0 == 0) ? 4 : 3;
#pragma unroll
    for (int k = 0; k < 4; ++k) {
        int iy = ybase - k;
#pragma unroll
        for (int lh = 0; lh < 2; ++lh) {
            int l = h * 2 + lh;
            int ix = xbase - l;
            bool ok = ((unsigned)iy < 1024u) && ((unsigned)ix < 1024u)
                      && (k < nk) && (l < nl);
            int off = iy * 1024 + ix;
            float v0 = ok ? 2.0f * in[off] - 1.0f : 0.f;
            float v1 = ok ? 2.0f * in[1048576 + off] - 1.0f : 0.f;
            float v2 = ok ? 2.0f * in[2097152 + off] - 1.0f : 0.f;
            int si = (k * 4 + l) * 128 + j;
            sgx[si]        = v0;
            sgx[2048 + si] = v1;
            sgx[4096 + si] = v2;
        }
    }

    if (t < 225) sw[t] = cw[t];
    if (t < 3)   sb[t] = cb[t];
    __syncthreads();

    // ---- A: key1 samples -> skv, partial logits -> plog1 (all blocks) ----
    key_stage(sw, sb, xa1, xb1, skv, lane, wv);
    __syncthreads();
    if (t < 100) {
        float s = 0.f;
        const float* kc = skc + t * 25;
#pragma unroll
        for (int i = 0; i < 24; ++i) s += kc[i] * skv[i];
        ST1(plog1 + blk * 128 + t, s);
    }
    gbar(ctr, blk, t);

    // ---- C' (replicated): reduce partials -> softmax -> kern1 -> w_eff ----
    if (t < 100) {
        const float* p = plog1 + t;
        float s0 = 0.f, s1 = 0.f, s2 = 0.f, s3 = 0.f;
#pragma unroll
        for (int b = 0; b < 32; ++b) {
            s0 += LD1(p + (4 * b + 0) * 128);
            s1 += LD1(p + (4 * b + 1) * 128);
            s2 += LD1(p + (4 * b + 2) * 128);
            s3 += LD1(p + (4 * b + 3) * 128);
        }
        slog[t] = (s0 + s1) + (s2 + s3);
    }
    __syncthreads();
    softmax_lds(slog, satt, lane, wv);
    if (t < 225) {
        float s = 0.f;
#pragma unroll
        for (int n = 0; n < 100; ++n) s += vals[n * 225 + t] * satt[n];
        sk1[t] = s;
    }
    __syncthreads();
    if (t < 225) {   // w_eff[co][ci][a][bb] = conv(convT(.,kern1)) composite
        int co = t / 75, rem = t % 75, ci = rem / 25, a = (rem % 25) / 5, bb = rem % 5;
        float s = 0.f;
#pragma unroll
        for (int c = 0; c < 5; ++c) {
            int u = c + 2 * a - 4;
            if ((unsigned)u >= 5u) continue;
#pragma unroll
            for (int d = 0; d < 5; ++d) {
                int v = d + 2 * bb - 4;
                if ((unsigned)v >= 5u) continue;
#pragma unroll
                for (int cm = 0; cm < 3; ++cm)
                    s += sk1[ci * 75 + cm * 25 + c * 5 + d] * cw[co * 75 + cm * 25 + u * 5 + v];
            }
        }
        sw[t] = s;    // nobody reads old sw in this phase
    }
    __syncthreads();

    // ---- D: key2 samples via w_eff -> skv, partials -> plog2 ----
    key_stage(sw, sb, xa2, xb2, skv, lane, wv);
    __syncthreads();
    if (t < 100) {
        float s = 0.f;
        const float* kc = skc + t * 25;
#pragma unroll
        for (int i = 0; i < 24; ++i) s += kc[i] * skv[i];
        ST1(plog2 + blk * 128 + t, s);
    }
    gbar(ctr + 256, blk, t);

    // ---- F' (replicated): reduce -> softmax -> kern2 -> composite tables ----
    if (t < 100) {
        const float* p = plog2 + t;
        float s0 = 0.f, s1 = 0.f, s2 = 0.f, s3 = 0.f;
#pragma unroll
        for (int b = 0; b < 32; ++b) {
            s0 += LD1(p + (4 * b + 0) * 128);
            s1 += LD1(p + (4 * b + 1) * 128);
            s2 += LD1(p + (4 * b + 2) * 128);
            s3 += LD1(p + (4 * b + 3) * 128);
        }
        slog[t] = (s0 + s1) + (s2 + s3);
    }
    __syncthreads();
    softmax_lds(slog, satt, lane, wv);
    if (t < 225) {
        float s = 0.f;
#pragma unroll
        for (int n = 0; n < 100; ++n) s += vals[n * 225 + t] * satt[n];
        sk2[t] = s;
    }
    __syncthreads();
    for (int idx = t; idx < 1521; idx += 256) {   // W
        int ci = idx / 507, rem = idx % 507, o = rem / 169;
        int ef = rem % 169, e = ef / 13, f = ef % 13;
        float s = 0.f;
#pragma unroll
        for (int c = 0; c < 5; ++c) {
            int a = e - 2 * c;
            if ((unsigned)a >= 5u) continue;
#pragma unroll
            for (int d = 0; d < 5; ++d) {
                int b2 = f - 2 * d;
                if ((unsigned)b2 >= 5u) continue;
#pragma unroll
                for (int cm = 0; cm < 3; ++cm)
                    s += sk1[ci * 75 + cm * 25 + c * 5 + d] * sk2[cm * 75 + o * 25 + a * 5 + b2];
            }
        }
        sW[idx] = s;
    }
    if (t < 117) {   // Wy
        int ci = t / 39, o = (t % 39) / 13, f = t % 13;
        float s = 0.f;
#pragma unroll
        for (int d = 0; d < 5; ++d) {
            int b2 = f - 2 * d;
            if ((unsigned)b2 >= 5u) continue;
#pragma unroll
            for (int cm = 0; cm < 3; ++cm)
                s += sk1[ci * 75 + cm * 25 + 5 + d] * sk2[cm * 75 + o * 25 + 20 + b2];
        }
        sWy[(ci * 3 + o) * 13 + f] = s;
    }
    if (t >= 128 && t < 245) {   // Wx
        int q = t - 128;
        int ci = q / 39, o = (q % 39) / 13, e = q % 13;
        float s = 0.f;
#pragma unroll
        for (int c = 0; c < 5; ++c) {
            int a = e - 2 * c;
            if ((unsigned)a >= 5u) continue;
#pragma unroll
            for (int cm = 0; cm < 3; ++cm)
                s += sk1[ci * 75 + cm * 25 + c * 5 + 1] * sk2[cm * 75 + o * 25 + a * 5 + 4];
        }
        sWx[(ci * 3 + o) * 13 + e] = s;
    }
    if (t >= 246 && t < 255) {   // Wxy
        int q = t - 246;
        int ci = q / 3, o = q % 3;
        float s = 0.f;
#pragma unroll
        for (int cm = 0; cm < 3; ++cm)
            s += sk1[ci * 75 + cm * 25 + 5 + 1] * sk2[cm * 75 + o * 25 + 20 + 4];
        sWxy[ci * 3 + o] = s;
    }
    __syncthreads();

    // ==== R19 MEASUREMENT: warm duplicate of C'->D->bar->F' (idempotent) ====
    // C'2
    if (t < 100) {
        const float* p = plog1 + t;
        float s0 = 0.f, s1 = 0.f, s2 = 0.f, s3 = 0.f;
#pragma unroll
        for (int b = 0; b < 32; ++b) {
            s0 += LD1(p + (4 * b + 0) * 128);
            s1 += LD1(p + (4 * b + 1) * 128);
            s2 += LD1(p + (4 * b + 2) * 128);
            s3 += LD1(p + (4 * b + 3) * 128);
        }
        slog[t] = (s0 + s1) + (s2 + s3);
    }
    __syncthreads();
    softmax_lds(slog, satt, lane, wv);
    if (t < 225) {
        float s = 0.f;
#pragma unroll
        for (int n = 0; n < 100; ++n) s += vals[n * 225 + t] * satt[n];
        sk1[t] = s;
    }
    __syncthreads();
    if (t < 225) {   // w_eff recompute (reads sk1/cw only -> idempotent)
        int co = t / 75, rem = t % 75, ci = rem / 25, a = (rem % 25) / 5, bb = rem % 5;
        float s = 0.f;
#pragma unroll
        for (int c = 0; c < 5; ++c) {
            int u = c + 2 * a - 4;
            if ((unsigned)u >= 5u) continue;
#pragma unroll
            for (int d = 0; d < 5; ++d) {
                int v = d + 2 * bb - 4;
                if ((unsigned)v >= 5u) continue;
#pragma unroll
                for (int cm = 0; cm < 3; ++cm)
                    s += sk1[ci * 75 + cm * 25 + c * 5 + d] * cw[co * 75 + cm * 25 + u * 5 + v];
            }
        }
        sw[t] = s;
    }
    __syncthreads();
    // D2
    key_stage(sw, sb, xa2, xb2, skv, lane, wv);
    __syncthreads();
    if (t < 100) {
        float s = 0.f;
        const float* kc = skc + t * 25;
#pragma unroll
        for (int i = 0; i < 24; ++i) s += kc[i] * skv[i];
        ST1(plog2 + blk * 128 + t, s);
    }
    gbar(ctr + 512, blk, t);
    // F'2
    if (t < 100) {
        const float* p = plog2 + t;
        float s0 = 0.f, s1 = 0.f, s2 = 0.f, s3 = 0.f;
#pragma unroll
        for (int b = 0; b < 32; ++b) {
            s0 += LD1(p + (4 * b + 0) * 128);
            s1 += LD1(p + (4 * b + 1) * 128);
            s2 += LD1(p + (4 * b + 2) * 128);
            s3 += LD1(p + (4 * b + 3) * 128);
        }
        slog[t] = (s0 + s1) + (s2 + s3);
    }
    __syncthreads();
    softmax_lds(slog, satt, lane, wv);
    if (t < 225) {
        float s = 0.f;
#pragma unroll
        for (int n = 0; n < 100; ++n) s += vals[n * 225 + t] * satt[n];
        sk2[t] = s;
    }
    __syncthreads();
    for (int idx = t; idx < 1521; idx += 256) {   // W recompute
        int ci = idx / 507, rem = idx % 507, o = rem / 169;
        int ef = rem % 169, e = ef / 13, f = ef % 13;
        float s = 0.f;
#pragma unroll
        for (int c = 0; c < 5; ++c) {
            int a = e - 2 * c;
            if ((unsigned)a >= 5u) continue;
#pragma unroll
            for (int d = 0; d < 5; ++d) {
                int b2 = f - 2 * d;
                if ((unsigned)b2 >= 5u) continue;
#pragma unroll
                for (int cm = 0; cm < 3; ++cm)
                    s += sk1[ci * 75 + cm * 25 + c * 5 + d] * sk2[cm * 75 + o * 25 + a * 5 + b2];
            }
        }
        sW[idx] = s;
    }
    if (t < 117) {   // Wy recompute
        int ci = t / 39, o = (t % 39) / 13, f = t % 13;
        float s = 0.f;
#pragma unroll
        for (int d = 0; d < 5; ++d) {
            int b2 = f - 2 * d;
            if ((unsigned)b2 >= 5u) continue;
#pragma unroll
            for (int cm = 0; cm < 3; ++cm)
                s += sk1[ci * 75 + cm * 25 + 5 + d] * sk2[cm * 75 + o * 25 + 20 + b2];
        }
        sWy[(ci * 3 + o) * 13 + f] = s;
    }
    if (t >= 128 && t < 245) {   // Wx recompute
        int q = t - 128;
        int ci = q / 39, o = (q % 39) / 13, e = q % 13;
        float s = 0.f;
#pragma unroll
        for (int c = 0; c < 5; ++c) {
            int a = e - 2 * c;
            if ((unsigned)a >= 5u) continue;
#pragma unroll
            for (int cm = 0; cm < 3; ++cm)
                s += sk1[ci * 75 + cm * 25 + c * 5 + 1] * sk2[cm * 75 + o * 25 + a * 5 + 4];
        }
        sWx[(ci * 3 + o) * 13 + e] = s;
    }
    if (t >= 246 && t < 255) {   // Wxy recompute
        int q = t - 246;
        int ci = q / 3, o = q % 3;
        float s = 0.f;
#pragma unroll
        for (int cm = 0; cm < 3; ++cm)
            s += sk1[ci * 75 + cm * 25 + 5 + 1] * sk2[cm * 75 + o * 25 + 20 + 4];
        sWxy[ci * 3 + o] = s;
    }
    __syncthreads();
    // ==== end duplicate ====

    // ---- G: final sampled composite convT + sigmoid (taps + tables in LDS) ----
    if (t < 128) {
        float a0 = 0.f, a1 = 0.f, a2 = 0.f;
#pragma unroll
        for (int k = 0; k < 4; ++k) {
            if (k < nk) {
                int e = r0 + 4 * k;
#pragma unroll
                for (int l = 0; l < 4; ++l) {
                    if (l < nl) {
                        int f = f0 + 4 * l;
                        int wi = e * 13 + f;
                        int si = (k * 4 + l) * 128 + j;
                        float x0 = sgx[si], x1 = sgx[2048 + si], x2 = sgx[4096 + si];
                        a0 += x0 * sW[wi]       + x1 * sW[507 + wi]  + x2 * sW[1014 + wi];
                        a1 += x0 * sW[169 + wi] + x1 * sW[676 + wi]  + x2 * sW[1183 + wi];
                        a2 += x0 * sW[338 + wi] + x1 * sW[845 + wi]  + x2 * sW[1352 + wi];
                    }
                }
            }
        }
        if (R == 0) {
            for (int l = 0; l < nl; ++l) {
                int ix = xbase - l;
                if ((unsigned)ix >= 1024u) continue;
                int f = f0 + 4 * l;
                float x0 = 2.0f * in[ix] - 1.0f;
                float x1 = 2.0f * in[1048576 + ix] - 1.0f;
                float x2 = 2.0f * in[2097152 + ix] - 1.0f;
                a0 -= x0 * sWy[f]      + x1 * sWy[39 + f] + x2 * sWy[78 + f];
                a1 -= x0 * sWy[13 + f] + x1 * sWy[52 + f] + x2 * sWy[91 + f];
                a2 -= x0 * sWy[26 + f] + x1 * sWy[65 + f] + x2 * sWy[104 + f];
            }
        }
        if (C == 0) {
            for (int k = 0; k < nk; ++k) {
                int iy = ybase - k;
                if ((unsigned)iy >= 1024u) continue;
                int e = r0 + 4 * k;
                int off = iy * 1024;
                float x0 = 2.0f * in[off] - 1.0f;
                float x1 = 2.0f * in[1048576 + off] - 1.0f;
                float x2 = 2.0f * in[2097152 + off] - 1.0f;
                a0 -= x0 * sWx[e]      + x1 * sWx[39 + e] + x2 * sWx[78 + e];
                a1 -= x0 * sWx[13 + e] + x1 * sWx[52 + e] + x2 * sWx[91 + e];
                a2 -= x0 * sWx[26 + e] + x1 * sWx[65 + e] + x2 * sWx[104 + e];
            }
        }
        if (R == 0 && C == 0) {
            float x0 = 2.0f * in[0] - 1.0f;
            float x1 = 2.0f * in[1048576] - 1.0f;
            float x2 = 2.0f * in[2097152] - 1.0f;
            a0 += x0 * sWxy[0] + x1 * sWxy[3] + x2 * sWxy[6];
            a1 += x0 * sWxy[1] + x1 * sWxy[4] + x2 * sWxy[7];
            a2 += x0 * sWxy[2] + x1 * sWxy[5] + x2 * sWxy[8];
        }
        int T = blk * 128 + j;
        out[T]             = sigmoidf_(a0);
        out[16384 + T]     = sigmoidf_(a1);
        out[2 * 16384 + T] = sigmoidf_(a2);
    }
}

extern "C" void kernel_launch(void* const* d_in, const int* in_sizes, int n_in,
                              void* d_out, int out_size, void* d_ws, size_t ws_size,
                              hipStream_t stream) {
    const float* in   = (const float*)d_in[0];   // [3,1024,1024]
    const float* cw   = (const float*)d_in[1];   // [3,3,5,5]
    const float* cb   = (const float*)d_in[2];   // [3]
    const float* keys = (const float*)d_in[3];   // [100,3072]
    const float* vals = (const float*)d_in[4];   // [100,225]
    float* out = (float*)d_out;                  // [3,128,128] fp32

    unsigned* ctr = (unsigned*)d_ws;             // 3 barriers x 1KB (store-based)
    float* wsf = (float*)((char*)d_ws + 8192);   // float scratch: 2 x 16384 plog

    hipMemsetAsync(d_ws, 0, 3072, stream);       // zero barrier state (3 regions)
    k_fused<<<GRID, 256, 0, stream>>>(in, cw, cb, keys, vals, out, wsf, ctr);
}

// Round 8
// 107.575 us; speedup vs baseline: 1.2517x; 1.2517x over previous
//
#include <hip/hip_runtime.h>
#include <hip/hip_bf16.h>

// R20: == R17 structure (2-barrier transposed-logit, dur 111.18) with the
// serial chains inside the replicated section shortened ==
// R19 bisect: warm duplicate of C'->D->bar->F' cost 22.1us => phase bodies
// are SERIAL-CHAIN dominated (not cold-miss). At 1 wave/SIMD (4 waves/CU,
// 128 blocks on 256 CUs) every dependent latency is fully exposed and most
// phases use <=2 of 4 waves. Changes (no structural change):
//  1. REDUCE SPLIT: waves 2-3 (idle before) take b=64..127; 64 loads/thread
//     = one vmcnt window; partials pr0/pr1 combined inside softmax.
//  2. TABLE SUBSET: block blk only uses W rows e = r0+4k (k<nk, fixed per
//     block) -> build 9*nk*13 <= 468 of 1521 W entries into compact
//     sWk[(ci*3+o)*nk*13 + k*13 + f]; Wx subset 9*nk; Wy/Wxy only in blk 0
//     (R==0 <=> blk==0). ~3.2x less table work, 2 not 6 outputs/thread.
//  3. G SPLIT over all 256 threads (R14-validated shape, taps from LDS sgx,
//     sga combine) + dual-accumulator kern matvec.
// Ledger (measured): agent acquire/release fences forbidden (R4); cross-block
// data sc1 relaxed-agent only (R8); no dynamic-indexed register arrays (R7);
// no rolled global-load loops (R11); entry prefetch of all static loads
// (R12); NO long-lived prefetch regs across barriers - stage via LDS
// (R14/R15); dur_us is ground truth, rocprof inflates poll loops ~5x,
// barrier ~1.4us (R16/R19 corrected); distributed barrier neutral (R18);
// warm C'+D+F' ~22us = serial chains (R19). Deadlock safety: 128 blocks x
// 256 thr, launch_bounds(256,1), ~43KB LDS -> co-resident on 256 CUs.
// Barrier state (2 x 1KB) zeroed by captured memset node each call.

#define GRID 128

#define LD1(p)     __hip_atomic_load((p), __ATOMIC_RELAXED, __HIP_MEMORY_SCOPE_AGENT)
#define ST1(p, v)  __hip_atomic_store((p), (v), __ATOMIC_RELAXED, __HIP_MEMORY_SCOPE_AGENT)

__device__ __forceinline__ float sigmoidf_(float z) {
    return 1.0f / (1.0f + expf(-z));
}

// base: 256 words (1KB). arrival[0..127]; release flag at word 160.
// No atomics anywhere: stores + loads only. (R12-validated, R17 form)
__device__ __forceinline__ void gbar(unsigned* base, int blk, int t) {
    asm volatile("s_waitcnt vmcnt(0)" ::: "memory");   // data sc1 stores visible
    __syncthreads();
    if (t == 0) ST1(base + blk, 1u);                   // arrival store, own word
    if (blk == 0) {
        if (t < 128) {                                 // 2 waves poll 128 words
            while (LD1(base + t) == 0u)
                __builtin_amdgcn_s_sleep(8);
        }
        __syncthreads();
        if (t == 0) ST1(base + 160, 1u);               // release flag, own line
    } else {
        if (t == 0) {
            while (LD1(base + 160) == 0u)
                __builtin_amdgcn_s_sleep(8);
        }
        __syncthreads();
    }
    asm volatile("" ::: "memory");
    __syncthreads();
}

// entry tap loads for one key stage (2 samples/wave; sample = blk*4+wv+rep*512)
__device__ __forceinline__ void key_prefetch(const float* __restrict__ in,
                                             int mul, int dbl, int blk,
                                             int lane, int wv,
                                             float xa[2], float xb[2]) {
#pragma unroll
    for (int rep = 0; rep < 2; ++rep) {
        int s = blk * 4 + wv + rep * 512;
        int ii = s >> 5, jj = s & 31;
        int qy = (ii * mul) >> 5, qx = (jj * mul) >> 5;
        int by = dbl ? 2 * qy : qy - 1;
        int bx = dbl ? 2 * qx : qx - 1;
        {
            int l = lane;                    // < 64 < 75: always a valid tap
            int ci = l / 25, rm = l % 25, r = rm / 5, cc = rm % 5;
            int y = by + r, x = bx + cc;
            xa[rep] = ((unsigned)y < 1024u && (unsigned)x < 1024u)
                      ? 2.0f * in[ci * 1048576 + y * 1024 + x] - 1.0f : 0.f;
        }
        xb[rep] = 0.f;
        if (lane < 11) {
            int l = lane + 64;
            int ci = l / 25, rm = l % 25, r = rm / 5, cc = rm % 5;
            int y = by + r, x = bx + cc;
            xb[rep] = ((unsigned)y < 1024u && (unsigned)x < 1024u)
                      ? 2.0f * in[ci * 1048576 + y * 1024 + x] - 1.0f : 0.f;
        }
    }
}

// key values from prefetched taps -> skv LDS (24 floats: [c*8 + rep*4 + wv])
__device__ __forceinline__ void key_stage(const float* __restrict__ sw,
                                          const float* __restrict__ sb,
                                          const float xa[2], const float xb[2],
                                          float* __restrict__ skv,
                                          int lane, int wv) {
#pragma unroll
    for (int rep = 0; rep < 2; ++rep) {
        float p0 = xa[rep] * sw[lane];
        float p1 = xa[rep] * sw[75 + lane];
        float p2 = xa[rep] * sw[150 + lane];
        if (lane < 11) {
            p0 += xb[rep] * sw[64 + lane];
            p1 += xb[rep] * sw[139 + lane];
            p2 += xb[rep] * sw[214 + lane];
        }
#pragma unroll
        for (int off = 32; off > 0; off >>= 1) {
            p0 += __shfl_xor(p0, off, 64);
            p1 += __shfl_xor(p1, off, 64);
            p2 += __shfl_xor(p2, off, 64);
        }
        if (lane == 0) {
            skv[0 * 8 + rep * 4 + wv] = sigmoidf_(p0 + sb[0]);
            skv[1 * 8 + rep * 4 + wv] = sigmoidf_(p1 + sb[1]);
            skv[2 * 8 + rep * 4 + wv] = sigmoidf_(p2 + sb[2]);
        }
    }
}

// 2-group split reduce of plog[128][128] -> pr0/pr1 (waves 0-1: b<64,
// waves 2-3: b>=64). 64 loads/thread = one vmcnt window.
__device__ __forceinline__ void reduce_split(const float* __restrict__ plog,
                                             float* __restrict__ pr0,
                                             float* __restrict__ pr1,
                                             int t) {
    int g = t >> 7, tq = t & 127;
    if (tq < 100) {
        const float* p = plog + tq + g * 64 * 128;
        float s0 = 0.f, s1 = 0.f, s2 = 0.f, s3 = 0.f;
#pragma unroll
        for (int b = 0; b < 16; ++b) {
            s0 += LD1(p + (4 * b + 0) * 128);
            s1 += LD1(p + (4 * b + 1) * 128);
            s2 += LD1(p + (4 * b + 2) * 128);
            s3 += LD1(p + (4 * b + 3) * 128);
        }
        (g ? pr1 : pr0)[tq] = (s0 + s1) + (s2 + s3);
    }
}

// softmax over pr0[i]+pr1[i], i<100 -> satt (LDS); runs in every block
__device__ __forceinline__ void softmax_lds(const float* __restrict__ pr0,
                                            const float* __restrict__ pr1,
                                            float* __restrict__ satt,
                                            int lane, int wv) {
    if (wv == 0) {
        float v1 = pr0[lane] + pr1[lane];
        float v2 = (lane + 64 < 100) ? pr0[lane + 64] + pr1[lane + 64] : -3.4e38f;
        float mx = fmaxf(v1, v2);
#pragma unroll
        for (int off = 32; off > 0; off >>= 1) mx = fmaxf(mx, __shfl_xor(mx, off, 64));
        float e1 = expf(v1 - mx);
        float e2 = (lane + 64 < 100) ? expf(v2 - mx) : 0.f;
        float s = e1 + e2;
#pragma unroll
        for (int off = 32; off > 0; off >>= 1) s += __shfl_xor(s, off, 64);
        float inv = 1.0f / s;
        satt[lane] = e1 * inv;
        if (lane + 64 < 100) satt[lane + 64] = e2 * inv;
    }
    __syncthreads();
}

__global__ __launch_bounds__(256, 1) void k_fused(
    const float* __restrict__ in, const float* __restrict__ cw,
    const float* __restrict__ cb, const float* __restrict__ keys,
    const float* __restrict__ vals, float* __restrict__ out,
    float* __restrict__ ws, unsigned* __restrict__ ctr)
{
    __shared__ float smem[10704];
    float* sk1  = smem;          // 225  kern1 (persists to tables)
    float* sk2  = smem + 232;    // 225  kern2
    float* satt = smem + 464;    // 100  softmax
    float* sw   = smem + 568;    // 225  conv weights, then w_eff
    float* sb   = smem + 800;    // 3    bias
    float* skv  = smem + 808;    // 24   block's key samples
    float* pr0  = smem + 832;    // 104  reduce partial (waves 0-1)
    float* pr1  = smem + 936;    // 104  reduce partial (waves 2-3)
    float* skc  = smem + 1040;   // 2500 keys cols [t*25 + c*8+r*4+w]
    float* sWk  = smem + 3540;   // 468  W subset [(ci*3+o)*nk13 + k*13 + f]
    float* sWxk = smem + 4008;   // 36   Wx subset [(ci*3+o)*nk + k]
    float* sWy  = smem + 4044;   // 117  (blk 0 only)
    float* sWxy = smem + 4164;   // 9    (blk 0 only)
    float* sga  = smem + 4176;   // 384  G half-combine
    float* sgx  = smem + 4560;   // 6144 G taps [((ch*4+k)*4+l)*128 + j]

    float* plog1 = ws;           // [128 blocks][128 stride], 100 used
    float* plog2 = ws + 16384;

    const int t = threadIdx.x, lane = t & 63, wv = t >> 6;
    const int blk = blockIdx.x;

    // ---- entry prefetch: key-stage taps (xa2/xb2 live across bar1, 4 regs) ----
    float xa1[2], xb1[2], xa2[2], xb2[2];
    key_prefetch(in, 510, 1, blk, lane, wv, xa1, xb1);
    key_prefetch(in, 1022, 0, blk, lane, wv, xa2, xb2);

    // ---- entry: keys columns for this block's 8 samples -> LDS (R14 fix) ----
    if (t < 100) {
        const float* kr = keys + t * 3072 + blk * 4;
#pragma unroll
        for (int c = 0; c < 3; ++c)
#pragma unroll
            for (int r = 0; r < 2; ++r) {
                float4 kk = *reinterpret_cast<const float4*>(kr + c * 1024 + r * 512);
                int o = t * 25 + c * 8 + r * 4;
                skc[o]     = kk.x;
                skc[o + 1] = kk.y;
                skc[o + 2] = kk.z;
                skc[o + 3] = kk.w;
            }
    }

    // ---- entry: stage G taps into LDS (registers die here; R14 lesson) ----
    const int j = t & 127, h = t >> 7;
    const int R = (blk * 4093) >> 7;
    const int C = (j * 4093) >> 7;
    const int ybase = (R + 6) >> 2, r0 = (R + 6) & 3, nk = (r0 == 0) ? 4 : 3;
    const int xbase = (C + 6) >> 2, f0 = (C + 6) & 3, nl = (f0 == 0) ? 4 : 3;
    const int nk13 = nk * 13;
#pragma unroll
    for (int k = 0; k < 4; ++k) {
        int iy = ybase - k;
#pragma unroll
        for (int lh = 0; lh < 2; ++lh) {
            int l = h * 2 + lh;
            int ix = xbase - l;
            bool ok = ((unsigned)iy < 1024u) && ((unsigned)ix < 1024u)
                      && (k < nk) && (l < nl);
            int off = iy * 1024 + ix;
            float v0 = ok ? 2.0f * in[off] - 1.0f : 0.f;
            float v1 = ok ? 2.0f * in[1048576 + off] - 1.0f : 0.f;
            float v2 = ok ? 2.0f * in[2097152 + off] - 1.0f : 0.f;
            int si = (k * 4 + l) * 128 + j;
            sgx[si]        = v0;
            sgx[2048 + si] = v1;
            sgx[4096 + si] = v2;
        }
    }

    if (t < 225) sw[t] = cw[t];
    if (t < 3)   sb[t] = cb[t];
    __syncthreads();

    // ---- A: key1 samples -> skv, partial logits -> plog1 (all blocks) ----
    key_stage(sw, sb, xa1, xb1, skv, lane, wv);
    __syncthreads();
    if (t < 100) {
        float s = 0.f;
        const float* kc = skc + t * 25;
#pragma unroll
        for (int i = 0; i < 24; ++i) s += kc[i] * skv[i];
        ST1(plog1 + blk * 128 + t, s);
    }
    gbar(ctr, blk, t);

    // ---- C' (replicated): split reduce -> softmax -> kern1 -> w_eff ----
    reduce_split(plog1, pr0, pr1, t);
    __syncthreads();
    softmax_lds(pr0, pr1, satt, lane, wv);
    if (t < 225) {   // kern1, dual accumulators
        float sa = 0.f, sb2 = 0.f;
#pragma unroll
        for (int n = 0; n < 50; ++n) {
            sa  += vals[(2 * n) * 225 + t] * satt[2 * n];
            sb2 += vals[(2 * n + 1) * 225 + t] * satt[2 * n + 1];
        }
        sk1[t] = sa + sb2;
    }
    __syncthreads();
    if (t < 225) {   // w_eff[co][ci][a][bb] = conv(convT(.,kern1)) composite
        int co = t / 75, rem = t % 75, ci = rem / 25, a = (rem % 25) / 5, bb = rem % 5;
        float s = 0.f;
#pragma unroll
        for (int c = 0; c < 5; ++c) {
            int u = c + 2 * a - 4;
            if ((unsigned)u >= 5u) continue;
#pragma unroll
            for (int d = 0; d < 5; ++d) {
                int v = d + 2 * bb - 4;
                if ((unsigned)v >= 5u) continue;
#pragma unroll
                for (int cm = 0; cm < 3; ++cm)
                    s += sk1[ci * 75 + cm * 25 + c * 5 + d] * cw[co * 75 + cm * 25 + u * 5 + v];
            }
        }
        sw[t] = s;    // nobody reads old sw in this phase
    }
    __syncthreads();

    // ---- D: key2 samples via w_eff -> skv, partials -> plog2 ----
    key_stage(sw, sb, xa2, xb2, skv, lane, wv);
    __syncthreads();
    if (t < 100) {
        float s = 0.f;
        const float* kc = skc + t * 25;
#pragma unroll
        for (int i = 0; i < 24; ++i) s += kc[i] * skv[i];
        ST1(plog2 + blk * 128 + t, s);
    }
    gbar(ctr + 256, blk, t);

    // ---- F' (replicated): split reduce -> softmax -> kern2 -> tables ----
    reduce_split(plog2, pr0, pr1, t);
    __syncthreads();
    softmax_lds(pr0, pr1, satt, lane, wv);
    if (t < 225) {   // kern2, dual accumulators
        float sa = 0.f, sb2 = 0.f;
#pragma unroll
        for (int n = 0; n < 50; ++n) {
            sa  += vals[(2 * n) * 225 + t] * satt[2 * n];
            sb2 += vals[(2 * n + 1) * 225 + t] * satt[2 * n + 1];
        }
        sk2[t] = sa + sb2;
    }
    __syncthreads();
    // W subset: only rows e = r0 + 4k (k < nk) that THIS block's G uses.
    for (int idx = t; idx < 9 * nk13; idx += 256) {
        int cio = idx / nk13, rem = idx % nk13;
        int k = rem / 13, f = rem % 13;
        int e = r0 + 4 * k;
        int ci = cio / 3, o = cio % 3;
        float s = 0.f;
#pragma unroll
        for (int c = 0; c < 5; ++c) {
            int a = e - 2 * c;
            if ((unsigned)a >= 5u) continue;
#pragma unroll
            for (int d = 0; d < 5; ++d) {
                int b2 = f - 2 * d;
                if ((unsigned)b2 >= 5u) continue;
#pragma unroll
                for (int cm = 0; cm < 3; ++cm)
                    s += sk1[ci * 75 + cm * 25 + c * 5 + d] * sk2[cm * 75 + o * 25 + a * 5 + b2];
            }
        }
        sWk[idx] = s;
    }
    if (t >= 128 && t < 128 + 9 * nk) {   // Wx subset (phantom col), e rows only
        int q = t - 128;
        int cio = q / nk, k = q % nk;
        int e = r0 + 4 * k;
        int ci = cio / 3, o = cio % 3;
        float s = 0.f;
#pragma unroll
        for (int c = 0; c < 5; ++c) {
            int a = e - 2 * c;
            if ((unsigned)a >= 5u) continue;
#pragma unroll
            for (int cm = 0; cm < 3; ++cm)
                s += sk1[ci * 75 + cm * 25 + c * 5 + 1] * sk2[cm * 75 + o * 25 + a * 5 + 4];
        }
        sWxk[cio * nk + k] = s;
    }
    if (blk == 0) {   // R==0 only for block 0: Wy full f-range + Wxy
        if (t < 117) {
            int ci = t / 39, o = (t % 39) / 13, f = t % 13;
            float s = 0.f;
#pragma unroll
            for (int d = 0; d < 5; ++d) {
                int b2 = f - 2 * d;
                if ((unsigned)b2 >= 5u) continue;
#pragma unroll
                for (int cm = 0; cm < 3; ++cm)
                    s += sk1[ci * 75 + cm * 25 + 5 + d] * sk2[cm * 75 + o * 25 + 20 + b2];
            }
            sWy[(ci * 3 + o) * 13 + f] = s;
        }
        if (t >= 224 && t < 233) {
            int q = t - 224;
            int ci = q / 3, o = q % 3;
            float s = 0.f;
#pragma unroll
            for (int cm = 0; cm < 3; ++cm)
                s += sk1[ci * 75 + cm * 25 + 5 + 1] * sk2[cm * 75 + o * 25 + 20 + 4];
            sWxy[ci * 3 + o] = s;
        }
    }
    __syncthreads();

    // ---- G: split over all 256 threads (h = tap half), compact tables ----
    {
        float a0 = 0.f, a1 = 0.f, a2 = 0.f;
#pragma unroll
        for (int k = 0; k < 4; ++k) {
            if (k < nk) {
#pragma unroll
                for (int lh = 0; lh < 2; ++lh) {
                    int l = h * 2 + lh;
                    if (l < nl) {
                        int f = f0 + 4 * l;
                        int wi = k * 13 + f;
                        int si = (k * 4 + l) * 128 + j;
                        float x0 = sgx[si], x1 = sgx[2048 + si], x2 = sgx[4096 + si];
                        a0 += x0 * sWk[wi]            + x1 * sWk[3 * nk13 + wi] + x2 * sWk[6 * nk13 + wi];
                        a1 += x0 * sWk[nk13 + wi]     + x1 * sWk[4 * nk13 + wi] + x2 * sWk[7 * nk13 + wi];
                        a2 += x0 * sWk[2 * nk13 + wi] + x1 * sWk[5 * nk13 + wi] + x2 * sWk[8 * nk13 + wi];
                    }
                }
            }
        }
        if (R == 0) {   // block 0: phantom-row correction, split by l-half
#pragma unroll
            for (int lh = 0; lh < 2; ++lh) {
                int l = h * 2 + lh;
                if (l < nl) {
                    int ix = xbase - l;
                    if ((unsigned)ix < 1024u) {
                        int f = f0 + 4 * l;
                        float x0 = 2.0f * in[ix] - 1.0f;
                        float x1 = 2.0f * in[1048576 + ix] - 1.0f;
                        float x2 = 2.0f * in[2097152 + ix] - 1.0f;
                        a0 -= x0 * sWy[f]      + x1 * sWy[39 + f] + x2 * sWy[78 + f];
                        a1 -= x0 * sWy[13 + f] + x1 * sWy[52 + f] + x2 * sWy[91 + f];
                        a2 -= x0 * sWy[26 + f] + x1 * sWy[65 + f] + x2 * sWy[104 + f];
                    }
                }
            }
        }
        if (C == 0 && h == 0) {   // j==0: phantom-col correction, once (h==0)
#pragma unroll
            for (int k = 0; k < 4; ++k) {
                if (k < nk) {
                    int iy = ybase - k;
                    if ((unsigned)iy < 1024u) {
                        int off = iy * 1024;
                        float x0 = 2.0f * in[off] - 1.0f;
                        float x1 = 2.0f * in[1048576 + off] - 1.0f;
                        float x2 = 2.0f * in[2097152 + off] - 1.0f;
                        a0 -= x0 * sWxk[k]          + x1 * sWxk[3 * nk + k] + x2 * sWxk[6 * nk + k];
                        a1 -= x0 * sWxk[nk + k]     + x1 * sWxk[4 * nk + k] + x2 * sWxk[7 * nk + k];
                        a2 -= x0 * sWxk[2 * nk + k] + x1 * sWxk[5 * nk + k] + x2 * sWxk[8 * nk + k];
                    }
                }
            }
        }
        if (R == 0 && C == 0 && h == 0) {
            float x0 = 2.0f * in[0] - 1.0f;
            float x1 = 2.0f * in[1048576] - 1.0f;
            float x2 = 2.0f * in[2097152] - 1.0f;
            a0 += x0 * sWxy[0] + x1 * sWxy[3] + x2 * sWxy[6];
            a1 += x0 * sWxy[1] + x1 * sWxy[4] + x2 * sWxy[7];
            a2 += x0 * sWxy[2] + x1 * sWxy[5] + x2 * sWxy[8];
        }
        if (h == 1) {
            sga[j] = a0; sga[128 + j] = a1; sga[256 + j] = a2;
        }
        __syncthreads();
        if (h == 0) {
            int T = blk * 128 + j;
            out[T]             = sigmoidf_(a0 + sga[j]);
            out[16384 + T]     = sigmoidf_(a1 + sga[128 + j]);
            out[2 * 16384 + T] = sigmoidf_(a2 + sga[256 + j]);
        }
    }
}

extern "C" void kernel_launch(void* const* d_in, const int* in_sizes, int n_in,
                              void* d_out, int out_size, void* d_ws, size_t ws_size,
                              hipStream_t stream) {
    const float* in   = (const float*)d_in[0];   // [3,1024,1024]
    const float* cw   = (const float*)d_in[1];   // [3,3,5,5]
    const float* cb   = (const float*)d_in[2];   // [3]
    const float* keys = (const float*)d_in[3];   // [100,3072]
    const float* vals = (const float*)d_in[4];   // [100,225]
    float* out = (float*)d_out;                  // [3,128,128] fp32

    unsigned* ctr = (unsigned*)d_ws;             // 2 barriers x 1KB (store-based)
    float* wsf = (float*)((char*)d_ws + 8192);   // float scratch: 2 x 16384 plog

    hipMemsetAsync(d_ws, 0, 2048, stream);       // zero barrier state
    k_fused<<<GRID, 256, 0, stream>>>(in, cw, cb, keys, vals, out, wsf, ctr);
}

// Round 9
// 106.076 us; speedup vs baseline: 1.2694x; 1.0141x over previous
//
#include <hip/hip_runtime.h>
#include <hip/hip_bf16.h>

// R21: == R20 math EXACTLY (dur 107.57, best) with ONE isolated change:
// CODE-SIZE REDUCTION. Twice-instantiated phase bodies deduplicated into
// __noinline__ functions; sgx G-tap LDS staging dropped (R15: staging vs
// direct-global G was neutral) -> G reads taps direct, entry loop deleted,
// LDS 45.6KB -> ~18.4KB.
// == Why ==
// The phase-latency model under-predicts measured phase cost ~4x, uniformly,
// invariant to data restructures (R12-R20). R19's "warm" duplicate was warm
// in DATA but COLD in CODE (new instruction addresses) and cost a full 22us.
// At 1 wave/SIMD there is no co-resident wave to share icache; the huge
// fully-unrolled straight-line kernel streams cold instructions the whole
// way. VALUBusy ~5% with no memory-boundness = front-end stall. Hypothesis:
// icache streaming is the hidden uniform tax. This round tests it by
// shrinking static code ~40% with bit-identical math.
// Pre-committed: dur 100-104 -> icache confirmed, keep shrinking (roll
// non-load loops, share more). dur 106-109 -> theory dead; next = fine
// per-phase bisect.
// Structure (R17/R20): 2-barrier transposed-logit.
//   entry: xa taps (float4 by value), keys cols -> skc, cw/cb -> LDS
//   A: key1 samples -> skv ; logit partials -> plog1        [all blocks]
//   bar1
//   C': split reduce -> softmax -> kern1 -> w_eff        [REPLICATED]
//   D: key2 via w_eff -> skv ; partials -> plog2            [all blocks]
//   bar2
//   F': split reduce -> softmax -> kern2 -> subset tables sWk/sWxk(/sWy/sWxy)
//   G: out = sigmoid(composite convT), 256-thr split, taps DIRECT from global
// Ledger (measured): agent acquire/release fences forbidden (R4); cross-block
// data sc1 relaxed-agent only (R8); no dynamic-indexed register arrays (R7);
// no rolled global-load loops (R11); entry prefetch of static loads (R12);
// NO long-lived prefetch regs across barriers - stage via LDS (R14/R15);
// dur_us is ground truth, rocprof inflates poll loops ~5x, barrier ~1.4us
// (R16/R19); distributed barrier neutral (R18); warm-dup 22us = serial/code
// cost (R19); reduce-split + table-subset + G-split won 3.6us (R20).
// Deadlock safety: 128 blocks x 256 thr, launch_bounds(256,1), ~18.4KB LDS
// -> co-resident on 256 CUs. Barrier state (2 x 1KB) zeroed each call.

#define GRID 128

#define LD1(p)     __hip_atomic_load((p), __ATOMIC_RELAXED, __HIP_MEMORY_SCOPE_AGENT)
#define ST1(p, v)  __hip_atomic_store((p), (v), __ATOMIC_RELAXED, __HIP_MEMORY_SCOPE_AGENT)

__device__ __forceinline__ float sigmoidf_(float z) {
    return 1.0f / (1.0f + expf(-z));
}

// base: 256 words (1KB). arrival[0..127]; release flag at word 160.
// No atomics anywhere: stores + loads only. (R12-validated, R17 form)
__device__ __forceinline__ void gbar(unsigned* base, int blk, int t) {
    asm volatile("s_waitcnt vmcnt(0)" ::: "memory");   // data sc1 stores visible
    __syncthreads();
    if (t == 0) ST1(base + blk, 1u);                   // arrival store, own word
    if (blk == 0) {
        if (t < 128) {                                 // 2 waves poll 128 words
            while (LD1(base + t) == 0u)
                __builtin_amdgcn_s_sleep(8);
        }
        __syncthreads();
        if (t == 0) ST1(base + 160, 1u);               // release flag, own line
    } else {
        if (t == 0) {
            while (LD1(base + 160) == 0u)
                __builtin_amdgcn_s_sleep(8);
        }
        __syncthreads();
    }
    asm volatile("" ::: "memory");
    __syncthreads();
}

// entry tap loads for one key stage; returns (xa0, xa1, xb0, xb1) in VGPRs.
// ONE code copy (noinline), called twice.
__device__ __attribute__((noinline)) float4
key_prefetch(const float* __restrict__ in, int mul, int dbl, int blk,
             int lane, int wv) {
    float xa[2], xb[2];
#pragma unroll
    for (int rep = 0; rep < 2; ++rep) {
        int s = blk * 4 + wv + rep * 512;
        int ii = s >> 5, jj = s & 31;
        int qy = (ii * mul) >> 5, qx = (jj * mul) >> 5;
        int by = dbl ? 2 * qy : qy - 1;
        int bx = dbl ? 2 * qx : qx - 1;
        {
            int l = lane;                    // < 64 < 75: always a valid tap
            int ci = l / 25, rm = l % 25, r = rm / 5, cc = rm % 5;
            int y = by + r, x = bx + cc;
            xa[rep] = ((unsigned)y < 1024u && (unsigned)x < 1024u)
                      ? 2.0f * in[ci * 1048576 + y * 1024 + x] - 1.0f : 0.f;
        }
        xb[rep] = 0.f;
        if (lane < 11) {
            int l = lane + 64;
            int ci = l / 25, rm = l % 25, r = rm / 5, cc = rm % 5;
            int y = by + r, x = bx + cc;
            xb[rep] = ((unsigned)y < 1024u && (unsigned)x < 1024u)
                      ? 2.0f * in[ci * 1048576 + y * 1024 + x] - 1.0f : 0.f;
        }
    }
    return make_float4(xa[0], xa[1], xb[0], xb[1]);
}

// key values from taps -> skv LDS (24 floats: [c*8 + rep*4 + wv]); one copy.
__device__ __attribute__((noinline)) void
key_stage(const float* __restrict__ sw, const float* __restrict__ sb,
          float xa0, float xa1, float xb0, float xb1,
          float* __restrict__ skv, int lane, int wv) {
    float xa[2] = {xa0, xa1}, xb[2] = {xb0, xb1};
#pragma unroll
    for (int rep = 0; rep < 2; ++rep) {
        float p0 = xa[rep] * sw[lane];
        float p1 = xa[rep] * sw[75 + lane];
        float p2 = xa[rep] * sw[150 + lane];
        if (lane < 11) {
            p0 += xb[rep] * sw[64 + lane];
            p1 += xb[rep] * sw[139 + lane];
            p2 += xb[rep] * sw[214 + lane];
        }
#pragma unroll
        for (int off = 32; off > 0; off >>= 1) {
            p0 += __shfl_xor(p0, off, 64);
            p1 += __shfl_xor(p1, off, 64);
            p2 += __shfl_xor(p2, off, 64);
        }
        if (lane == 0) {
            skv[0 * 8 + rep * 4 + wv] = sigmoidf_(p0 + sb[0]);
            skv[1 * 8 + rep * 4 + wv] = sigmoidf_(p1 + sb[1]);
            skv[2 * 8 + rep * 4 + wv] = sigmoidf_(p2 + sb[2]);
        }
    }
}

// logit partial (skc x skv) -> plog row; one copy.
__device__ __attribute__((noinline)) void
logit_partial(const float* __restrict__ skc, const float* __restrict__ skv,
              float* __restrict__ plog, int blk, int t) {
    if (t < 100) {
        float s = 0.f;
        const float* kc = skc + t * 25;
#pragma unroll
        for (int i = 0; i < 24; ++i) s += kc[i] * skv[i];
        ST1(plog + blk * 128 + t, s);
    }
}

// 2-group split reduce of plog[128][128] -> pr0/pr1; one copy.
__device__ __attribute__((noinline)) void
reduce_split(const float* __restrict__ plog, float* __restrict__ pr0,
             float* __restrict__ pr1, int t) {
    int g = t >> 7, tq = t & 127;
    if (tq < 100) {
        const float* p = plog + tq + g * 64 * 128;
        float s0 = 0.f, s1 = 0.f, s2 = 0.f, s3 = 0.f;
#pragma unroll
        for (int b = 0; b < 16; ++b) {
            s0 += LD1(p + (4 * b + 0) * 128);
            s1 += LD1(p + (4 * b + 1) * 128);
            s2 += LD1(p + (4 * b + 2) * 128);
            s3 += LD1(p + (4 * b + 3) * 128);
        }
        (g ? pr1 : pr0)[tq] = (s0 + s1) + (s2 + s3);
    }
}

// softmax over pr0[i]+pr1[i], i<100 -> satt; one copy (has syncthreads).
__device__ __attribute__((noinline)) void
softmax_lds(const float* __restrict__ pr0, const float* __restrict__ pr1,
            float* __restrict__ satt, int lane, int wv) {
    if (wv == 0) {
        float v1 = pr0[lane] + pr1[lane];
        float v2 = (lane + 64 < 100) ? pr0[lane + 64] + pr1[lane + 64] : -3.4e38f;
        float mx = fmaxf(v1, v2);
#pragma unroll
        for (int off = 32; off > 0; off >>= 1) mx = fmaxf(mx, __shfl_xor(mx, off, 64));
        float e1 = expf(v1 - mx);
        float e2 = (lane + 64 < 100) ? expf(v2 - mx) : 0.f;
        float s = e1 + e2;
#pragma unroll
        for (int off = 32; off > 0; off >>= 1) s += __shfl_xor(s, off, 64);
        float inv = 1.0f / s;
        satt[lane] = e1 * inv;
        if (lane + 64 < 100) satt[lane + 64] = e2 * inv;
    }
    __syncthreads();
}

// kern matvec: dst[t] = sum_n vals[n][t]*satt[n], dual accumulators; one copy.
__device__ __attribute__((noinline)) void
kern_phase(const float* __restrict__ vals, const float* __restrict__ satt,
           float* __restrict__ dst, int t) {
    if (t < 225) {
        float sa = 0.f, sb2 = 0.f;
#pragma unroll
        for (int n = 0; n < 50; ++n) {
            sa  += vals[(2 * n) * 225 + t] * satt[2 * n];
            sb2 += vals[(2 * n + 1) * 225 + t] * satt[2 * n + 1];
        }
        dst[t] = sa + sb2;
    }
}

__global__ __launch_bounds__(256, 1) void k_fused(
    const float* __restrict__ in, const float* __restrict__ cw,
    const float* __restrict__ cb, const float* __restrict__ keys,
    const float* __restrict__ vals, float* __restrict__ out,
    float* __restrict__ ws, unsigned* __restrict__ ctr)
{
    __shared__ float smem[4560];
    float* sk1  = smem;          // 225  kern1 (persists to tables)
    float* sk2  = smem + 232;    // 225  kern2
    float* satt = smem + 464;    // 100  softmax
    float* sw   = smem + 568;    // 225  conv weights, then w_eff
    float* sb   = smem + 800;    // 3    bias
    float* skv  = smem + 808;    // 24   block's key samples
    float* pr0  = smem + 832;    // 104  reduce partial (waves 0-1)
    float* pr1  = smem + 936;    // 104  reduce partial (waves 2-3)
    float* skc  = smem + 1040;   // 2500 keys cols [t*25 + c*8+r*4+w]
    float* sWk  = smem + 3540;   // 468  W subset [(ci*3+o)*nk13 + k*13 + f]
    float* sWxk = smem + 4008;   // 36   Wx subset [(ci*3+o)*nk + k]
    float* sWy  = smem + 4044;   // 117  (blk 0 only)
    float* sWxy = smem + 4164;   // 9    (blk 0 only)
    float* sga  = smem + 4176;   // 384  G half-combine

    float* plog1 = ws;           // [128 blocks][128 stride], 100 used
    float* plog2 = ws + 16384;

    const int t = threadIdx.x, lane = t & 63, wv = t >> 6;
    const int blk = blockIdx.x;

    // ---- entry prefetch: key-stage taps (s2v = 4 regs live across bar1) ----
    float4 s1v = key_prefetch(in, 510, 1, blk, lane, wv);
    float4 s2v = key_prefetch(in, 1022, 0, blk, lane, wv);

    // ---- entry: keys columns for this block's 8 samples -> LDS (R14 fix) ----
    if (t < 100) {
        const float* kr = keys + t * 3072 + blk * 4;
#pragma unroll
        for (int c = 0; c < 3; ++c)
#pragma unroll
            for (int r = 0; r < 2; ++r) {
                float4 kk = *reinterpret_cast<const float4*>(kr + c * 1024 + r * 512);
                int o = t * 25 + c * 8 + r * 4;
                skc[o]     = kk.x;
                skc[o + 1] = kk.y;
                skc[o + 2] = kk.z;
                skc[o + 3] = kk.w;
            }
    }

    // ---- G geometry (taps read DIRECT from global in G; R15: staging neutral) --
    const int j = t & 127, h = t >> 7;
    const int R = (blk * 4093) >> 7;
    const int C = (j * 4093) >> 7;
    const int ybase = (R + 6) >> 2, r0 = (R + 6) & 3, nk = (r0 == 0) ? 4 : 3;
    const int xbase = (C + 6) >> 2, f0 = (C + 6) & 3, nl = (f0 == 0) ? 4 : 3;
    const int nk13 = nk * 13;

    if (t < 225) sw[t] = cw[t];
    if (t < 3)   sb[t] = cb[t];
    __syncthreads();

    // ---- A: key1 samples -> skv, partial logits -> plog1 (all blocks) ----
    key_stage(sw, sb, s1v.x, s1v.y, s1v.z, s1v.w, skv, lane, wv);
    __syncthreads();
    logit_partial(skc, skv, plog1, blk, t);
    gbar(ctr, blk, t);

    // ---- C' (replicated): split reduce -> softmax -> kern1 -> w_eff ----
    reduce_split(plog1, pr0, pr1, t);
    __syncthreads();
    softmax_lds(pr0, pr1, satt, lane, wv);
    kern_phase(vals, satt, sk1, t);
    __syncthreads();
    if (t < 225) {   // w_eff[co][ci][a][bb] = conv(convT(.,kern1)) composite
        int co = t / 75, rem = t % 75, ci = rem / 25, a = (rem % 25) / 5, bb = rem % 5;
        float s = 0.f;
#pragma unroll
        for (int c = 0; c < 5; ++c) {
            int u = c + 2 * a - 4;
            if ((unsigned)u >= 5u) continue;
#pragma unroll
            for (int d = 0; d < 5; ++d) {
                int v = d + 2 * bb - 4;
                if ((unsigned)v >= 5u) continue;
#pragma unroll
                for (int cm = 0; cm < 3; ++cm)
                    s += sk1[ci * 75 + cm * 25 + c * 5 + d] * cw[co * 75 + cm * 25 + u * 5 + v];
            }
        }
        sw[t] = s;    // nobody reads old sw in this phase
    }
    __syncthreads();

    // ---- D: key2 samples via w_eff -> skv, partials -> plog2 ----
    key_stage(sw, sb, s2v.x, s2v.y, s2v.z, s2v.w, skv, lane, wv);
    __syncthreads();
    logit_partial(skc, skv, plog2, blk, t);
    gbar(ctr + 256, blk, t);

    // ---- F' (replicated): split reduce -> softmax -> kern2 -> tables ----
    reduce_split(plog2, pr0, pr1, t);
    __syncthreads();
    softmax_lds(pr0, pr1, satt, lane, wv);
    kern_phase(vals, satt, sk2, t);
    __syncthreads();
    // W subset: only rows e = r0 + 4k (k < nk) that THIS block's G uses.
    for (int idx = t; idx < 9 * nk13; idx += 256) {
        int cio = idx / nk13, rem = idx % nk13;
        int k = rem / 13, f = rem % 13;
        int e = r0 + 4 * k;
        int ci = cio / 3, o = cio % 3;
        float s = 0.f;
#pragma unroll
        for (int c = 0; c < 5; ++c) {
            int a = e - 2 * c;
            if ((unsigned)a >= 5u) continue;
#pragma unroll
            for (int d = 0; d < 5; ++d) {
                int b2 = f - 2 * d;
                if ((unsigned)b2 >= 5u) continue;
#pragma unroll
                for (int cm = 0; cm < 3; ++cm)
                    s += sk1[ci * 75 + cm * 25 + c * 5 + d] * sk2[cm * 75 + o * 25 + a * 5 + b2];
            }
        }
        sWk[idx] = s;
    }
    if (t >= 128 && t < 128 + 9 * nk) {   // Wx subset (phantom col), e rows only
        int q = t - 128;
        int cio = q / nk, k = q % nk;
        int e = r0 + 4 * k;
        int ci = cio / 3, o = cio % 3;
        float s = 0.f;
#pragma unroll
        for (int c = 0; c < 5; ++c) {
            int a = e - 2 * c;
            if ((unsigned)a >= 5u) continue;
#pragma unroll
            for (int cm = 0; cm < 3; ++cm)
                s += sk1[ci * 75 + cm * 25 + c * 5 + 1] * sk2[cm * 75 + o * 25 + a * 5 + 4];
        }
        sWxk[cio * nk + k] = s;
    }
    if (blk == 0) {   // R==0 only for block 0: Wy full f-range + Wxy
        if (t < 117) {
            int ci = t / 39, o = (t % 39) / 13, f = t % 13;
            float s = 0.f;
#pragma unroll
            for (int d = 0; d < 5; ++d) {
                int b2 = f - 2 * d;
                if ((unsigned)b2 >= 5u) continue;
#pragma unroll
                for (int cm = 0; cm < 3; ++cm)
                    s += sk1[ci * 75 + cm * 25 + 5 + d] * sk2[cm * 75 + o * 25 + 20 + b2];
            }
            sWy[(ci * 3 + o) * 13 + f] = s;
        }
        if (t >= 224 && t < 233) {
            int q = t - 224;
            int ci = q / 3, o = q % 3;
            float s = 0.f;
#pragma unroll
            for (int cm = 0; cm < 3; ++cm)
                s += sk1[ci * 75 + cm * 25 + 5 + 1] * sk2[cm * 75 + o * 25 + 20 + 4];
            sWxy[ci * 3 + o] = s;
        }
    }
    __syncthreads();

    // ---- G: split over all 256 threads (h = tap half), taps direct global ----
    {
        float a0 = 0.f, a1 = 0.f, a2 = 0.f;
#pragma unroll
        for (int k = 0; k < 4; ++k) {
            if (k < nk) {
                int iy = ybase - k;
                if ((unsigned)iy < 1024u) {
#pragma unroll
                    for (int lh = 0; lh < 2; ++lh) {
                        int l = h * 2 + lh;
                        if (l < nl) {
                            int ix = xbase - l;
                            if ((unsigned)ix < 1024u) {
                                int f = f0 + 4 * l;
                                int wi = k * 13 + f;
                                int off = iy * 1024 + ix;
                                float x0 = 2.0f * in[off] - 1.0f;
                                float x1 = 2.0f * in[1048576 + off] - 1.0f;
                                float x2 = 2.0f * in[2097152 + off] - 1.0f;
                                a0 += x0 * sWk[wi]            + x1 * sWk[3 * nk13 + wi] + x2 * sWk[6 * nk13 + wi];
                                a1 += x0 * sWk[nk13 + wi]     + x1 * sWk[4 * nk13 + wi] + x2 * sWk[7 * nk13 + wi];
                                a2 += x0 * sWk[2 * nk13 + wi] + x1 * sWk[5 * nk13 + wi] + x2 * sWk[8 * nk13 + wi];
                            }
                        }
                    }
                }
            }
        }
        if (R == 0) {   // block 0: phantom-row correction, split by l-half
#pragma unroll
            for (int lh = 0; lh < 2; ++lh) {
                int l = h * 2 + lh;
                if (l < nl) {
                    int ix = xbase - l;
                    if ((unsigned)ix < 1024u) {
                        int f = f0 + 4 * l;
                        float x0 = 2.0f * in[ix] - 1.0f;
                        float x1 = 2.0f * in[1048576 + ix] - 1.0f;
                        float x2 = 2.0f * in[2097152 + ix] - 1.0f;
                        a0 -= x0 * sWy[f]      + x1 * sWy[39 + f] + x2 * sWy[78 + f];
                        a1 -= x0 * sWy[13 + f] + x1 * sWy[52 + f] + x2 * sWy[91 + f];
                        a2 -= x0 * sWy[26 + f] + x1 * sWy[65 + f] + x2 * sWy[104 + f];
                    }
                }
            }
        }
        if (C == 0 && h == 0) {   // j==0: phantom-col correction, once (h==0)
#pragma unroll
            for (int k = 0; k < 4; ++k) {
                if (k < nk) {
                    int iy = ybase - k;
                    if ((unsigned)iy < 1024u) {
                        int off = iy * 1024;
                        float x0 = 2.0f * in[off] - 1.0f;
                        float x1 = 2.0f * in[1048576 + off] - 1.0f;
                        float x2 = 2.0f * in[2097152 + off] - 1.0f;
                        a0 -= x0 * sWxk[k]          + x1 * sWxk[3 * nk + k] + x2 * sWxk[6 * nk + k];
                        a1 -= x0 * sWxk[nk + k]     + x1 * sWxk[4 * nk + k] + x2 * sWxk[7 * nk + k];
                        a2 -= x0 * sWxk[2 * nk + k] + x1 * sWxk[5 * nk + k] + x2 * sWxk[8 * nk + k];
                    }
                }
            }
        }
        if (R == 0 && C == 0 && h == 0) {
            float x0 = 2.0f * in[0] - 1.0f;
            float x1 = 2.0f * in[1048576] - 1.0f;
            float x2 = 2.0f * in[2097152] - 1.0f;
            a0 += x0 * sWxy[0] + x1 * sWxy[3] + x2 * sWxy[6];
            a1 += x0 * sWxy[1] + x1 * sWxy[4] + x2 * sWxy[7];
            a2 += x0 * sWxy[2] + x1 * sWxy[5] + x2 * sWxy[8];
        }
        if (h == 1) {
            sga[j] = a0; sga[128 + j] = a1; sga[256 + j] = a2;
        }
        __syncthreads();
        if (h == 0) {
            int T = blk * 128 + j;
            out[T]             = sigmoidf_(a0 + sga[j]);
            out[16384 + T]     = sigmoidf_(a1 + sga[128 + j]);
            out[2 * 16384 + T] = sigmoidf_(a2 + sga[256 + j]);
        }
    }
}

extern "C" void kernel_launch(void* const* d_in, const int* in_sizes, int n_in,
                              void* d_out, int out_size, void* d_ws, size_t ws_size,
                              hipStream_t stream) {
    const float* in   = (const float*)d_in[0];   // [3,1024,1024]
    const float* cw   = (const float*)d_in[1];   // [3,3,5,5]
    const float* cb   = (const float*)d_in[2];   // [3]
    const float* keys = (const float*)d_in[3];   // [100,3072]
    const float* vals = (const float*)d_in[4];   // [100,225]
    float* out = (float*)d_out;                  // [3,128,128] fp32

    unsigned* ctr = (unsigned*)d_ws;             // 2 barriers x 1KB (store-based)
    float* wsf = (float*)((char*)d_ws + 8192);   // float scratch: 2 x 16384 plog

    hipMemsetAsync(d_ws, 0, 2048, stream);       // zero barrier state
    k_fused<<<GRID, 256, 0, stream>>>(in, cw, cb, keys, vals, out, wsf, ctr);
}

// Round 10
// 101.188 us; speedup vs baseline: 1.3307x; 1.0483x over previous
//
#include <hip/hip_runtime.h>
#include <hip/hip_bf16.h>

// R22: == R21 structure/math (2-barrier transposed-logit, noinline dedup;
// dur 106.08, best) with ONE lever: 512-THREAD BLOCKS (8 waves = 2/SIMD)
// + re-distribution of the remaining serial work ==
// R21 post-mortem: 30% code cut -> only -1.5us; icache theory dead. The
// surviving explanation for the uniform ~4x phase-latency tax: occupancy.
// 256 thr/block = 1 wave/SIMD = ZERO latency hiding; every LDS/L2/MALL/
// shuffle latency is fully exposed in every phase (signature: invariant to
// data layout and code size; R20's work-distribution helped). Fix: 2 waves
// per SIMD so stalls co-issue, plus halve/quarter the real chains:
//   - key stages: 8 waves -> 1 sample/wave (was 2 serial reps/wave)
//   - reduce: 4 groups x 32 rows (was 2 x 64); softmax sums 4 partials
//   - G: 4-way l-split (1 l x <=4 k per thread) + sga combine
// Also visible this round: the ~69.5us dur-kernel offset contains a harness
// 268MB fillBufferAligned re-poison (~41us @ 81% peak) - fixed cost, not
// kernel-addressable. Addressable budget: kernel ~36.6us = phases ~34 +
// barriers ~2.7.
// Pre-committed: dur 100-103 -> TLP confirmed, push further (more waves /
// merge phases). ~106 neutral -> tax is per-phase fixed overhead -> merge
// phases & cut syncs. absmax <=0.004 ok (reassociation; R13's 0.0039 passed).
// Ledger (measured): agent acquire/release fences forbidden (R4); cross-block
// data sc1 relaxed-agent only (R8); no dynamic-indexed register arrays (R7);
// no rolled global-load loops (R11); entry prefetch of static loads (R12);
// NO long-lived prefetch regs across barriers - stage via LDS (R14/R15);
// dur_us is ground truth, rocprof inflates poll loops ~5x, barrier ~1.4us
// (R16/R19); distributed barrier neutral (R18); warm-dup 22us (R19);
// reduce-split+table-subset+G-split -3.6us (R20); code-size -1.5us (R21).
// Deadlock safety: 128 blocks x 512 thr, launch_bounds(512,1), ~22KB LDS,
// VGPR ~76 << 256 -> 1 block/CU co-resident. Barrier state (2x1KB) zeroed.

#define GRID 128

#define LD1(p)     __hip_atomic_load((p), __ATOMIC_RELAXED, __HIP_MEMORY_SCOPE_AGENT)
#define ST1(p, v)  __hip_atomic_store((p), (v), __ATOMIC_RELAXED, __HIP_MEMORY_SCOPE_AGENT)

__device__ __forceinline__ float sigmoidf_(float z) {
    return 1.0f / (1.0f + expf(-z));
}

// base: 256 words (1KB). arrival[0..127]; release flag at word 160.
// No atomics anywhere: stores + loads only. (R12-validated, R17 form)
__device__ __forceinline__ void gbar(unsigned* base, int blk, int t) {
    asm volatile("s_waitcnt vmcnt(0)" ::: "memory");   // data sc1 stores visible
    __syncthreads();
    if (t == 0) ST1(base + blk, 1u);                   // arrival store, own word
    if (blk == 0) {
        if (t < 128) {                                 // 2 waves poll 128 words
            while (LD1(base + t) == 0u)
                __builtin_amdgcn_s_sleep(8);
        }
        __syncthreads();
        if (t == 0) ST1(base + 160, 1u);               // release flag, own line
    } else {
        if (t == 0) {
            while (LD1(base + 160) == 0u)
                __builtin_amdgcn_s_sleep(8);
        }
        __syncthreads();
    }
    asm volatile("" ::: "memory");
    __syncthreads();
}

// entry tap loads, ONE sample per wave (sample = blk*4 + wrow + rep*512).
__device__ __attribute__((noinline)) float2
key_prefetch(const float* __restrict__ in, int mul, int dbl, int blk,
             int lane, int wrow, int rep) {
    int s = blk * 4 + wrow + rep * 512;
    int ii = s >> 5, jj = s & 31;
    int qy = (ii * mul) >> 5, qx = (jj * mul) >> 5;
    int by = dbl ? 2 * qy : qy - 1;
    int bx = dbl ? 2 * qx : qx - 1;
    float xa, xb = 0.f;
    {
        int l = lane;                    // < 64 < 75: always a valid tap
        int ci = l / 25, rm = l % 25, r = rm / 5, cc = rm % 5;
        int y = by + r, x = bx + cc;
        xa = ((unsigned)y < 1024u && (unsigned)x < 1024u)
             ? 2.0f * in[ci * 1048576 + y * 1024 + x] - 1.0f : 0.f;
    }
    if (lane < 11) {
        int l = lane + 64;
        int ci = l / 25, rm = l % 25, r = rm / 5, cc = rm % 5;
        int y = by + r, x = bx + cc;
        xb = ((unsigned)y < 1024u && (unsigned)x < 1024u)
             ? 2.0f * in[ci * 1048576 + y * 1024 + x] - 1.0f : 0.f;
    }
    return make_float2(xa, xb);
}

// key value from taps -> skv LDS ([c*8 + rep*4 + wrow]); one sample per wave.
__device__ __attribute__((noinline)) void
key_stage(const float* __restrict__ sw, const float* __restrict__ sb,
          float xa, float xb, float* __restrict__ skv,
          int lane, int wrow, int rep) {
    float p0 = xa * sw[lane];
    float p1 = xa * sw[75 + lane];
    float p2 = xa * sw[150 + lane];
    if (lane < 11) {
        p0 += xb * sw[64 + lane];
        p1 += xb * sw[139 + lane];
        p2 += xb * sw[214 + lane];
    }
#pragma unroll
    for (int off = 32; off > 0; off >>= 1) {
        p0 += __shfl_xor(p0, off, 64);
        p1 += __shfl_xor(p1, off, 64);
        p2 += __shfl_xor(p2, off, 64);
    }
    if (lane == 0) {
        skv[0 * 8 + rep * 4 + wrow] = sigmoidf_(p0 + sb[0]);
        skv[1 * 8 + rep * 4 + wrow] = sigmoidf_(p1 + sb[1]);
        skv[2 * 8 + rep * 4 + wrow] = sigmoidf_(p2 + sb[2]);
    }
}

// logit partial (skc x skv) -> plog row; one copy.
__device__ __attribute__((noinline)) void
logit_partial(const float* __restrict__ skc, const float* __restrict__ skv,
              float* __restrict__ plog, int blk, int t) {
    if (t < 100) {
        float s = 0.f;
        const float* kc = skc + t * 25;
#pragma unroll
        for (int i = 0; i < 24; ++i) s += kc[i] * skv[i];
        ST1(plog + blk * 128 + t, s);
    }
}

// 4-group split reduce of plog[128][128] -> pr[4][104]; 32 loads/thread.
__device__ __attribute__((noinline)) void
reduce_split(const float* __restrict__ plog, float* __restrict__ pr, int t) {
    int g = t >> 7, tq = t & 127;
    if (tq < 100) {
        const float* p = plog + tq + g * 32 * 128;
        float s0 = 0.f, s1 = 0.f, s2 = 0.f, s3 = 0.f;
#pragma unroll
        for (int b = 0; b < 8; ++b) {
            s0 += LD1(p + (4 * b + 0) * 128);
            s1 += LD1(p + (4 * b + 1) * 128);
            s2 += LD1(p + (4 * b + 2) * 128);
            s3 += LD1(p + (4 * b + 3) * 128);
        }
        pr[g * 104 + tq] = (s0 + s1) + (s2 + s3);
    }
}

// softmax over sum of 4 partials, i<100 -> satt; one copy (has syncthreads).
__device__ __attribute__((noinline)) void
softmax_lds(const float* __restrict__ pr, float* __restrict__ satt,
            int lane, int wv) {
    if (wv == 0) {
        float v1 = (pr[lane] + pr[104 + lane]) + (pr[208 + lane] + pr[312 + lane]);
        float v2 = -3.4e38f;
        if (lane + 64 < 100) {
            int q = lane + 64;
            v2 = (pr[q] + pr[104 + q]) + (pr[208 + q] + pr[312 + q]);
        }
        float mx = fmaxf(v1, v2);
#pragma unroll
        for (int off = 32; off > 0; off >>= 1) mx = fmaxf(mx, __shfl_xor(mx, off, 64));
        float e1 = expf(v1 - mx);
        float e2 = (lane + 64 < 100) ? expf(v2 - mx) : 0.f;
        float s = e1 + e2;
#pragma unroll
        for (int off = 32; off > 0; off >>= 1) s += __shfl_xor(s, off, 64);
        float inv = 1.0f / s;
        satt[lane] = e1 * inv;
        if (lane + 64 < 100) satt[lane + 64] = e2 * inv;
    }
    __syncthreads();
}

// kern matvec: dst[t] = sum_n vals[n][t]*satt[n], dual accumulators; one copy.
__device__ __attribute__((noinline)) void
kern_phase(const float* __restrict__ vals, const float* __restrict__ satt,
           float* __restrict__ dst, int t) {
    if (t < 225) {
        float sa = 0.f, sb2 = 0.f;
#pragma unroll
        for (int n = 0; n < 50; ++n) {
            sa  += vals[(2 * n) * 225 + t] * satt[2 * n];
            sb2 += vals[(2 * n + 1) * 225 + t] * satt[2 * n + 1];
        }
        dst[t] = sa + sb2;
    }
}

__global__ __launch_bounds__(512, 1) void k_fused(
    const float* __restrict__ in, const float* __restrict__ cw,
    const float* __restrict__ cb, const float* __restrict__ keys,
    const float* __restrict__ vals, float* __restrict__ out,
    float* __restrict__ ws, unsigned* __restrict__ ctr)
{
    __shared__ float smem[5536];
    float* sk1  = smem;          // 225  kern1 (persists to tables)
    float* sk2  = smem + 232;    // 225  kern2
    float* satt = smem + 464;    // 100  softmax
    float* sw   = smem + 568;    // 225  conv weights, then w_eff
    float* sb   = smem + 800;    // 3    bias
    float* skv  = smem + 808;    // 24   block's key samples
    float* pr   = smem + 832;    // 416  reduce partials [4][104]
    float* skc  = smem + 1248;   // 2500 keys cols [t*25 + c*8+r*4+w]
    float* sWk  = smem + 3748;   // 468  W subset [(ci*3+o)*nk13 + k*13 + f]
    float* sWxk = smem + 4216;   // 36   Wx subset [(ci*3+o)*nk + k]
    float* sWy  = smem + 4252;   // 117  (blk 0 only)
    float* sWxy = smem + 4372;   // 9    (blk 0 only)
    float* sga  = smem + 4384;   // 1152 G combine [(h-1)*384 + ch*128 + j]

    float* plog1 = ws;           // [128 blocks][128 stride], 100 used
    float* plog2 = ws + 16384;

    const int t = threadIdx.x, lane = t & 63, wv = t >> 6;
    const int wrow = wv & 3, rep = wv >> 2;
    const int blk = blockIdx.x;

    // ---- entry prefetch: one sample per wave (s2v = 2 regs across bar1) ----
    float2 s1v = key_prefetch(in, 510, 1, blk, lane, wrow, rep);
    float2 s2v = key_prefetch(in, 1022, 0, blk, lane, wrow, rep);

    // ---- entry: keys columns for this block's 8 samples -> LDS (R14 fix) ----
    if (t < 100) {
        const float* kr = keys + t * 3072 + blk * 4;
#pragma unroll
        for (int c = 0; c < 3; ++c)
#pragma unroll
            for (int r = 0; r < 2; ++r) {
                float4 kk = *reinterpret_cast<const float4*>(kr + c * 1024 + r * 512);
                int o = t * 25 + c * 8 + r * 4;
                skc[o]     = kk.x;
                skc[o + 1] = kk.y;
                skc[o + 2] = kk.z;
                skc[o + 3] = kk.w;
            }
    }

    // ---- G geometry (j = output col, h = l-slot 0..3; taps direct global) ----
    const int j = t & 127, h = t >> 7;
    const int R = (blk * 4093) >> 7;
    const int C = (j * 4093) >> 7;
    const int ybase = (R + 6) >> 2, r0 = (R + 6) & 3, nk = (r0 == 0) ? 4 : 3;
    const int xbase = (C + 6) >> 2, f0 = (C + 6) & 3, nl = (f0 == 0) ? 4 : 3;
    const int nk13 = nk * 13;

    if (t < 225) sw[t] = cw[t];
    if (t < 3)   sb[t] = cb[t];
    __syncthreads();

    // ---- A: key1 samples -> skv, partial logits -> plog1 (all blocks) ----
    key_stage(sw, sb, s1v.x, s1v.y, skv, lane, wrow, rep);
    __syncthreads();
    logit_partial(skc, skv, plog1, blk, t);
    gbar(ctr, blk, t);

    // ---- C' (replicated): split reduce -> softmax -> kern1 -> w_eff ----
    reduce_split(plog1, pr, t);
    __syncthreads();
    softmax_lds(pr, satt, lane, wv);
    kern_phase(vals, satt, sk1, t);
    __syncthreads();
    if (t < 225) {   // w_eff[co][ci][a][bb] = conv(convT(.,kern1)) composite
        int co = t / 75, rem = t % 75, ci = rem / 25, a = (rem % 25) / 5, bb = rem % 5;
        float s = 0.f;
#pragma unroll
        for (int c = 0; c < 5; ++c) {
            int u = c + 2 * a - 4;
            if ((unsigned)u >= 5u) continue;
#pragma unroll
            for (int d = 0; d < 5; ++d) {
                int v = d + 2 * bb - 4;
                if ((unsigned)v >= 5u) continue;
#pragma unroll
                for (int cm = 0; cm < 3; ++cm)
                    s += sk1[ci * 75 + cm * 25 + c * 5 + d] * cw[co * 75 + cm * 25 + u * 5 + v];
            }
        }
        sw[t] = s;    // nobody reads old sw in this phase
    }
    __syncthreads();

    // ---- D: key2 samples via w_eff -> skv, partials -> plog2 ----
    key_stage(sw, sb, s2v.x, s2v.y, skv, lane, wrow, rep);
    __syncthreads();
    logit_partial(skc, skv, plog2, blk, t);
    gbar(ctr + 256, blk, t);

    // ---- F' (replicated): split reduce -> softmax -> kern2 -> tables ----
    reduce_split(plog2, pr, t);
    __syncthreads();
    softmax_lds(pr, satt, lane, wv);
    kern_phase(vals, satt, sk2, t);
    __syncthreads();
    // W subset: only rows e = r0 + 4k (k < nk) that THIS block's G uses.
    for (int idx = t; idx < 9 * nk13; idx += 512) {
        int cio = idx / nk13, rem = idx % nk13;
        int k = rem / 13, f = rem % 13;
        int e = r0 + 4 * k;
        int ci = cio / 3, o = cio % 3;
        float s = 0.f;
#pragma unroll
        for (int c = 0; c < 5; ++c) {
            int a = e - 2 * c;
            if ((unsigned)a >= 5u) continue;
#pragma unroll
            for (int d = 0; d < 5; ++d) {
                int b2 = f - 2 * d;
                if ((unsigned)b2 >= 5u) continue;
#pragma unroll
                for (int cm = 0; cm < 3; ++cm)
                    s += sk1[ci * 75 + cm * 25 + c * 5 + d] * sk2[cm * 75 + o * 25 + a * 5 + b2];
            }
        }
        sWk[idx] = s;
    }
    if (t >= 472 && t < 472 + 9 * nk) {   // Wx subset (phantom col), idle threads
        int q = t - 472;
        int cio = q / nk, k = q % nk;
        int e = r0 + 4 * k;
        int ci = cio / 3, o = cio % 3;
        float s = 0.f;
#pragma unroll
        for (int c = 0; c < 5; ++c) {
            int a = e - 2 * c;
            if ((unsigned)a >= 5u) continue;
#pragma unroll
            for (int cm = 0; cm < 3; ++cm)
                s += sk1[ci * 75 + cm * 25 + c * 5 + 1] * sk2[cm * 75 + o * 25 + a * 5 + 4];
        }
        sWxk[cio * nk + k] = s;
    }
    if (blk == 0) {   // R==0 only for block 0: Wy full f-range + Wxy
        if (t >= 256 && t < 256 + 117) {
            int q = t - 256;
            int ci = q / 39, o = (q % 39) / 13, f = q % 13;
            float s = 0.f;
#pragma unroll
            for (int d = 0; d < 5; ++d) {
                int b2 = f - 2 * d;
                if ((unsigned)b2 >= 5u) continue;
#pragma unroll
                for (int cm = 0; cm < 3; ++cm)
                    s += sk1[ci * 75 + cm * 25 + 5 + d] * sk2[cm * 75 + o * 25 + 20 + b2];
            }
            sWy[(ci * 3 + o) * 13 + f] = s;
        }
        if (t >= 384 && t < 393) {
            int q = t - 384;
            int ci = q / 3, o = q % 3;
            float s = 0.f;
#pragma unroll
            for (int cm = 0; cm < 3; ++cm)
                s += sk1[ci * 75 + cm * 25 + 5 + 1] * sk2[cm * 75 + o * 25 + 20 + 4];
            sWxy[ci * 3 + o] = s;
        }
    }
    __syncthreads();

    // ---- G: 4-way split (h = l-slot), taps direct global, sga combine ----
    {
        float a0 = 0.f, a1 = 0.f, a2 = 0.f;
        const int l = h;
        if (l < nl) {
            int ix = xbase - l;
            if ((unsigned)ix < 1024u) {
                int f = f0 + 4 * l;
#pragma unroll
                for (int k = 0; k < 4; ++k) {
                    if (k < nk) {
                        int iy = ybase - k;
                        if ((unsigned)iy < 1024u) {
                            int wi = k * 13 + f;
                            int off = iy * 1024 + ix;
                            float x0 = 2.0f * in[off] - 1.0f;
                            float x1 = 2.0f * in[1048576 + off] - 1.0f;
                            float x2 = 2.0f * in[2097152 + off] - 1.0f;
                            a0 += x0 * sWk[wi]            + x1 * sWk[3 * nk13 + wi] + x2 * sWk[6 * nk13 + wi];
                            a1 += x0 * sWk[nk13 + wi]     + x1 * sWk[4 * nk13 + wi] + x2 * sWk[7 * nk13 + wi];
                            a2 += x0 * sWk[2 * nk13 + wi] + x1 * sWk[5 * nk13 + wi] + x2 * sWk[8 * nk13 + wi];
                        }
                    }
                }
                if (R == 0) {   // block 0: phantom-row correction for own l
                    float x0 = 2.0f * in[ix] - 1.0f;
                    float x1 = 2.0f * in[1048576 + ix] - 1.0f;
                    float x2 = 2.0f * in[2097152 + ix] - 1.0f;
                    a0 -= x0 * sWy[f]      + x1 * sWy[39 + f] + x2 * sWy[78 + f];
                    a1 -= x0 * sWy[13 + f] + x1 * sWy[52 + f] + x2 * sWy[91 + f];
                    a2 -= x0 * sWy[26 + f] + x1 * sWy[65 + f] + x2 * sWy[104 + f];
                }
            }
        }
        if (C == 0 && h == 0) {   // j==0: phantom-col correction, once
#pragma unroll
            for (int k = 0; k < 4; ++k) {
                if (k < nk) {
                    int iy = ybase - k;
                    if ((unsigned)iy < 1024u) {
                        int off = iy * 1024;
                        float x0 = 2.0f * in[off] - 1.0f;
                        float x1 = 2.0f * in[1048576 + off] - 1.0f;
                        float x2 = 2.0f * in[2097152 + off] - 1.0f;
                        a0 -= x0 * sWxk[k]          + x1 * sWxk[3 * nk + k] + x2 * sWxk[6 * nk + k];
                        a1 -= x0 * sWxk[nk + k]     + x1 * sWxk[4 * nk + k] + x2 * sWxk[7 * nk + k];
                        a2 -= x0 * sWxk[2 * nk + k] + x1 * sWxk[5 * nk + k] + x2 * sWxk[8 * nk + k];
                    }
                }
            }
        }
        if (R == 0 && C == 0 && h == 0) {
            float x0 = 2.0f * in[0] - 1.0f;
            float x1 = 2.0f * in[1048576] - 1.0f;
            float x2 = 2.0f * in[2097152] - 1.0f;
            a0 += x0 * sWxy[0] + x1 * sWxy[3] + x2 * sWxy[6];
            a1 += x0 * sWxy[1] + x1 * sWxy[4] + x2 * sWxy[7];
            a2 += x0 * sWxy[2] + x1 * sWxy[5] + x2 * sWxy[8];
        }
        if (h > 0) {
            int base = (h - 1) * 384;
            sga[base + j] = a0; sga[base + 128 + j] = a1; sga[base + 256 + j] = a2;
        }
        __syncthreads();
        if (h == 0) {
            int T = blk * 128 + j;
            float b0 = a0 + sga[j]       + sga[384 + j]       + sga[768 + j];
            float b1 = a1 + sga[128 + j] + sga[384 + 128 + j] + sga[768 + 128 + j];
            float b2 = a2 + sga[256 + j] + sga[384 + 256 + j] + sga[768 + 256 + j];
            out[T]             = sigmoidf_(b0);
            out[16384 + T]     = sigmoidf_(b1);
            out[2 * 16384 + T] = sigmoidf_(b2);
        }
    }
}

extern "C" void kernel_launch(void* const* d_in, const int* in_sizes, int n_in,
                              void* d_out, int out_size, void* d_ws, size_t ws_size,
                              hipStream_t stream) {
    const float* in   = (const float*)d_in[0];   // [3,1024,1024]
    const float* cw   = (const float*)d_in[1];   // [3,3,5,5]
    const float* cb   = (const float*)d_in[2];   // [3]
    const float* keys = (const float*)d_in[3];   // [100,3072]
    const float* vals = (const float*)d_in[4];   // [100,225]
    float* out = (float*)d_out;                  // [3,128,128] fp32

    unsigned* ctr = (unsigned*)d_ws;             // 2 barriers x 1KB (store-based)
    float* wsf = (float*)((char*)d_ws + 8192);   // float scratch: 2 x 16384 plog

    hipMemsetAsync(d_ws, 0, 2048, stream);       // zero barrier state
    k_fused<<<GRID, 512, 0, stream>>>(in, cw, cb, keys, vals, out, wsf, ctr);
}